// Round 15
// baseline (220.591 us; speedup 1.0000x reference)
//
#include <hip/hip_runtime.h>
#include <cstdint>
#include <cstddef>

#define DIM 128
#define HEADS 4

typedef __attribute__((ext_vector_type(8))) short bf16x8;
typedef __attribute__((ext_vector_type(4))) float f32x4;

__device__ __forceinline__ ushort f2bf(float x) {
    union { float f; uint32_t u; } v; v.f = x;
    uint32_t r = v.u + 0x7FFFu + ((v.u >> 16) & 1u);   // RNE
    return (ushort)(r >> 16);
}
__device__ __forceinline__ float bf2f(ushort h) {
    union { uint32_t u; float f; } v; v.u = ((uint32_t)h) << 16; return v.f;
}

// ---------------------------------------------------------------------------
// prep: fused wtrans (blocks 0..191) + count_degree (blocks 192..)
// wtrans: W[k][col] f32 -> Wt[w][col][k] bf16 hi/lo (transposed for B-frags)
// ---------------------------------------------------------------------------
__global__ __launch_bounds__(256)
void prep(const float* __restrict__ qW, const float* __restrict__ kW,
          const float* __restrict__ vW,
          ushort* __restrict__ WtHi, ushort* __restrict__ WtLo,
          const int* __restrict__ rows, int* __restrict__ degree, int E)
{
    int b = blockIdx.x;
    if (b < 192) {
        int t = b * 256 + threadIdx.x;           // 0..49151
        int w = t >> 14;
        int rem = t & 16383;
        int col = rem >> 7;
        int k = rem & 127;
        const float* W = (w == 0) ? qW : (w == 1) ? kW : vW;
        float x = W[k * DIM + col];
        ushort hi = f2bf(x);
        ushort lo = f2bf(x - bf2f(hi));
        WtHi[t] = hi;                            // [w][col][k]
        WtLo[t] = lo;
    } else {
        int e = (b - 192) * 256 + threadIdx.x;
        if (e < E) atomicAdd(&degree[rows[e]], 1);
    }
}

// ---------------------------------------------------------------------------
// qkv_fused v7: R5/R12 structure (57.7us measured) + T14 async-STAGE split:
// chunk c+1's global loads are ISSUED into registers right after chunk c's
// post-stage barrier, so HBM latency hides under chunk c's MFMA phase
// instead of serializing at the next iteration's stage step.
// Same addresses, same conversion ops/order, same MFMA order -> bit-exact.
// 256 thr = 4 waves (2M x 2N), block = 64 rows x 64 cols (blockIdx.y half).
// ---------------------------------------------------------------------------
#define APAD 40   // 32 k + 8 pad (ushorts); row stride 80B

__global__ __launch_bounds__(256)
void qkv_fused(const float* __restrict__ emb,
               const ushort* __restrict__ WtHi, const ushort* __restrict__ WtLo,
               ushort* __restrict__ Qb, ushort* __restrict__ KVb, int N)
{
    __shared__ ushort Ahi[64 * APAD], Alo[64 * APAD];          // 5120B each
    __shared__ ushort Bhi[3 * 64 * APAD], Blo[3 * 64 * APAD];  // 15360B each

    const int tid = threadIdx.x;
    const int wv = tid >> 6;
    const int ln = tid & 63;
    const int l15 = ln & 15;
    const int l4 = ln >> 4;
    const int wm = wv >> 1;             // wave row group (32 rows)
    const int wn = wv & 1;              // wave col group (32 cols)
    const int m0 = blockIdx.x * 64;
    const int c0 = blockIdx.y * 64;     // col half

    // ---- constant per-thread staging coordinates ----
    const int arow = tid >> 2;                   // 0..63
    const int ak8  = (tid & 3) * 8;              // 0,8,16,24
    const bool aok = (m0 + arow < N);
    const float* asrc = emb + (size_t)(m0 + arow) * DIM + ak8;

    int bw[3], bu[3];
    size_t bg[3];
#pragma unroll
    for (int p = 0; p < 3; p++) {
        int idx = tid + p * 256;
        int flat = idx * 8;
        int w = flat >> 11;
        int rem = flat & 2047;
        int col = rem >> 5;
        int kk8 = rem & 31;
        bw[p] = w;
        bg[p] = (size_t)w * 16384 + (size_t)(c0 + col) * DIM + kk8;  // + c*32
        bu[p] = (w * 64 + col) * APAD + kk8;
    }

    // ---- prefetch registers ----
    float4 pa0, pa1;
    uint4 pbh[3], pbl[3];

    // prologue: load chunk 0
    pa0 = make_float4(0.f, 0.f, 0.f, 0.f);
    pa1 = pa0;
    if (aok) {
        pa0 = *(const float4*)(asrc);
        pa1 = *(const float4*)(asrc + 4);
    }
#pragma unroll
    for (int p = 0; p < 3; p++) {
        pbh[p] = *(const uint4*)(WtHi + bg[p]);
        pbl[p] = *(const uint4*)(WtLo + bg[p]);
    }

    f32x4 acc[3][2][2] = {};            // [wsel][fr][n]

    for (int c = 0; c < 4; c++) {       // k chunk: k = c*32 .. +32
        if (c) __syncthreads();         // all waves done reading prior LDS
        // ---- stage from regs: A convert f32 -> bf16 hi/lo ----
        {
            ushort4 h0, l0, h1, l1;
            h0.x = f2bf(pa0.x); l0.x = f2bf(pa0.x - bf2f(h0.x));
            h0.y = f2bf(pa0.y); l0.y = f2bf(pa0.y - bf2f(h0.y));
            h0.z = f2bf(pa0.z); l0.z = f2bf(pa0.z - bf2f(h0.z));
            h0.w = f2bf(pa0.w); l0.w = f2bf(pa0.w - bf2f(h0.w));
            h1.x = f2bf(pa1.x); l1.x = f2bf(pa1.x - bf2f(h1.x));
            h1.y = f2bf(pa1.y); l1.y = f2bf(pa1.y - bf2f(h1.y));
            h1.z = f2bf(pa1.z); l1.z = f2bf(pa1.z - bf2f(h1.z));
            h1.w = f2bf(pa1.w); l1.w = f2bf(pa1.w - bf2f(h1.w));
            int u = arow * APAD + ak8;
            *(ushort4*)(Ahi + u) = h0; *(ushort4*)(Ahi + u + 4) = h1;
            *(ushort4*)(Alo + u) = l0; *(ushort4*)(Alo + u + 4) = l1;
        }
#pragma unroll
        for (int p = 0; p < 3; p++) {
            *(uint4*)(Bhi + bu[p]) = pbh[p];
            *(uint4*)(Blo + bu[p]) = pbl[p];
        }
        __syncthreads();

        // ---- T14: issue next chunk's loads NOW (hide under MFMA phase) ----
        if (c < 3) {
            pa0 = make_float4(0.f, 0.f, 0.f, 0.f);
            pa1 = pa0;
            if (aok) {
                pa0 = *(const float4*)(asrc + (c + 1) * 32);
                pa1 = *(const float4*)(asrc + (c + 1) * 32 + 4);
            }
#pragma unroll
            for (int p = 0; p < 3; p++) {
                pbh[p] = *(const uint4*)(WtHi + bg[p] + (c + 1) * 32);
                pbl[p] = *(const uint4*)(WtLo + bg[p] + (c + 1) * 32);
            }
        }

        // ---- MFMA: A frag row=wm*32+fr*16+l15, k=l4*8..+8 ----
        bf16x8 ah[2], al[2];
#pragma unroll
        for (int fr = 0; fr < 2; fr++) {
            int u = (wm * 32 + fr * 16 + l15) * APAD + l4 * 8;
            ah[fr] = *(bf16x8*)(Ahi + u);
            al[fr] = *(bf16x8*)(Alo + u);
        }
#pragma unroll
        for (int w = 0; w < 3; w++) {
#pragma unroll
            for (int n = 0; n < 2; n++) {
                int u = (w * 64 + wn * 32 + n * 16 + l15) * APAD + l4 * 8;
                bf16x8 bh = *(bf16x8*)(Bhi + u);
                bf16x8 bl = *(bf16x8*)(Blo + u);
#pragma unroll
                for (int fr = 0; fr < 2; fr++) {
                    acc[w][fr][n] = __builtin_amdgcn_mfma_f32_16x16x32_bf16(ah[fr], bh, acc[w][fr][n], 0, 0, 0);
                    acc[w][fr][n] = __builtin_amdgcn_mfma_f32_16x16x32_bf16(al[fr], bh, acc[w][fr][n], 0, 0, 0);
                    acc[w][fr][n] = __builtin_amdgcn_mfma_f32_16x16x32_bf16(ah[fr], bl, acc[w][fr][n], 0, 0, 0);
                }
            }
        }
    }

    // ---- epilogue: C/D layout col=lane&15, row=(lane>>4)*4+j ----
#pragma unroll
    for (int w = 0; w < 3; w++) {
#pragma unroll
        for (int fr = 0; fr < 2; fr++) {
            int rbase = m0 + wm * 32 + fr * 16 + l4 * 4;
#pragma unroll
            for (int n = 0; n < 2; n++) {
                int col = c0 + wn * 32 + n * 16 + l15;
#pragma unroll
                for (int j = 0; j < 4; j++) {
                    int r = rbase + j;
                    if (r < N) {
                        ushort val = f2bf(acc[w][fr][n][j]);
                        if (w == 0) Qb[(size_t)r * DIM + col] = val;
                        else        KVb[(size_t)r * 256 + (w - 1) * 128 + col] = val;
                    }
                }
            }
        }
    }
}

// ---------------------------------------------------------------------------
// CSR build: scanA (per-1024 exclusive scan + raw segment totals) then
// scanC (merged scanB: each block tree-reduces segSums[0..bid) itself).
// ---------------------------------------------------------------------------
__global__ __launch_bounds__(256)
void scanA(const int* __restrict__ degree, int* __restrict__ rowPtr,
           int* __restrict__ blockSums, int N)
{
    __shared__ int s[256];
    const int tid = threadIdx.x;
    const int base = blockIdx.x * 1024 + tid * 4;
    int d[4];
    int tsum = 0;
#pragma unroll
    for (int i = 0; i < 4; i++) {
        d[i] = (base + i < N) ? degree[base + i] : 0;
        tsum += d[i];
    }
    s[tid] = tsum;
    __syncthreads();
    for (int off = 1; off < 256; off <<= 1) {
        int v = (tid >= off) ? s[tid - off] : 0;
        __syncthreads();
        s[tid] += v;
        __syncthreads();
    }
    if (tid == 255) blockSums[blockIdx.x] = s[255];   // raw block total
    int running = s[tid] - tsum;
#pragma unroll
    for (int i = 0; i < 4; i++) {
        if (base + i < N) rowPtr[base + i] = running;
        running += d[i];
    }
}

__global__ __launch_bounds__(256)
void scanC(int* __restrict__ rowPtr, const int* __restrict__ blockSums,
           int* __restrict__ cursor, int N, int E, int nb)
{
    __shared__ int s[128];
    const int tid = threadIdx.x;
    const int bid = blockIdx.x;
    if (tid < 128) {
        int lim = (bid < nb) ? bid : nb;
        s[tid] = (tid < lim) ? blockSums[tid] : 0;
    }
    __syncthreads();
    for (int off = 64; off > 0; off >>= 1) {
        if (tid < off) s[tid] += s[tid + off];
        __syncthreads();
    }
    const int off = s[0];
    const int base = bid * 1024 + tid * 4;
#pragma unroll
    for (int i = 0; i < 4; i++) {
        int idx = base + i;
        if (idx < N) {
            int v = rowPtr[idx] + off;
            rowPtr[idx] = v;
            cursor[idx] = v;
        }
    }
    if (bid == 0 && tid == 0) rowPtr[N] = E;
}

// fill_perm: pack (edge id, col) into one int2 -> single 8B scattered store.
__global__ __launch_bounds__(256)
void fill_perm(const int* __restrict__ rows, const int* __restrict__ cols,
               int* __restrict__ cursor, int2* __restrict__ edgeInfo, int E)
{
    int e = blockIdx.x * 256 + threadIdx.x;
    if (e >= E) return;
    int pos = atomicAdd(&cursor[rows[e]], 1);
    edgeInfo[pos] = make_int2(e, cols[e]);
}

// ---------------------------------------------------------------------------
// csr_fused: 16 lanes per node (8 dims/lane), 4 nodes per wave. Edge loop
// UNROLL-4 (avg degree = 4): up to 16 independent gathers in flight/node.
// Per-edge accumulation order sequential in p -> bit-exact.
// edgeInfo int2 = (e, col): one 8B broadcast load per edge.
// ---------------------------------------------------------------------------
__global__ __launch_bounds__(256)
void csr_fused(const ushort* __restrict__ Qb, const ushort* __restrict__ KVb,
               const int* __restrict__ rowPtr, const int2* __restrict__ edgeInfo,
               float* __restrict__ attBuf, float* __restrict__ invNorm,
               float* __restrict__ out, int N)
{
    int t = blockIdx.x * 256 + threadIdx.x;
    int node = t >> 4;
    int lane = t & 15;                  // 16 lanes/node
    if (node >= N) return;

    const int start = rowPtr[node];
    const int end   = rowPtr[node + 1];
    const int h = lane >> 2;            // head (4 lanes each)

    const ushort* qp = Qb + (size_t)node * DIM + lane * 8;
    ushort4 qu0 = *(const ushort4*)(qp);
    ushort4 qu1 = *(const ushort4*)(qp + 4);
    float q[8] = {bf2f(qu0.x), bf2f(qu0.y), bf2f(qu0.z), bf2f(qu0.w),
                  bf2f(qu1.x), bf2f(qu1.y), bf2f(qu1.z), bf2f(qu1.w)};

    float norm = 0.f;
    float acc[8] = {0.f, 0.f, 0.f, 0.f, 0.f, 0.f, 0.f, 0.f};

    int p = start;
    for (; p + 4 <= end; p += 4) {
        int2 ei[4];
#pragma unroll
        for (int u = 0; u < 4; u++) ei[u] = edgeInfo[p + u];
        ushort4 ka[4], kb[4], va[4], vb[4];
#pragma unroll
        for (int u = 0; u < 4; u++) {
            const ushort* kv = KVb + (size_t)ei[u].y * 256 + lane * 8;
            ka[u] = *(const ushort4*)(kv);
            kb[u] = *(const ushort4*)(kv + 4);
            va[u] = *(const ushort4*)(kv + 128);
            vb[u] = *(const ushort4*)(kv + 132);
        }
        float d[4];
#pragma unroll
        for (int u = 0; u < 4; u++) {
            d[u] = bf2f(ka[u].x) * q[0] + bf2f(ka[u].y) * q[1]
                 + bf2f(ka[u].z) * q[2] + bf2f(ka[u].w) * q[3]
                 + bf2f(kb[u].x) * q[4] + bf2f(kb[u].y) * q[5]
                 + bf2f(kb[u].z) * q[6] + bf2f(kb[u].w) * q[7];
        }
#pragma unroll
        for (int u = 0; u < 4; u++) d[u] += __shfl_xor(d[u], 1, 64);
#pragma unroll
        for (int u = 0; u < 4; u++) d[u] += __shfl_xor(d[u], 2, 64);
        float ex[4];
#pragma unroll
        for (int u = 0; u < 4; u++) {
            float dd = fminf(fmaxf(d[u], -10.f), 10.f);
            ex[u] = __expf(dd);
        }
        if ((lane & 3) == 0) {
#pragma unroll
            for (int u = 0; u < 4; u++)
                attBuf[(size_t)ei[u].x * HEADS + h] = ex[u];
        }
#pragma unroll
        for (int u = 0; u < 4; u++) {
            norm += ex[u];
            acc[0] += ex[u] * bf2f(va[u].x);
            acc[1] += ex[u] * bf2f(va[u].y);
            acc[2] += ex[u] * bf2f(va[u].z);
            acc[3] += ex[u] * bf2f(va[u].w);
            acc[4] += ex[u] * bf2f(vb[u].x);
            acc[5] += ex[u] * bf2f(vb[u].y);
            acc[6] += ex[u] * bf2f(vb[u].z);
            acc[7] += ex[u] * bf2f(vb[u].w);
        }
    }
    for (; p < end; p++) {
        int2 ei = edgeInfo[p];
        const ushort* kv = KVb + (size_t)ei.y * 256 + lane * 8;
        ushort4 ka = *(const ushort4*)(kv);
        ushort4 kb = *(const ushort4*)(kv + 4);
        ushort4 va = *(const ushort4*)(kv + 128);
        ushort4 vb = *(const ushort4*)(kv + 132);
        float d = bf2f(ka.x) * q[0] + bf2f(ka.y) * q[1]
                + bf2f(ka.z) * q[2] + bf2f(ka.w) * q[3]
                + bf2f(kb.x) * q[4] + bf2f(kb.y) * q[5]
                + bf2f(kb.z) * q[6] + bf2f(kb.w) * q[7];
        d += __shfl_xor(d, 1, 64);
        d += __shfl_xor(d, 2, 64);
        d = fminf(fmaxf(d, -10.f), 10.f);
        float ex = __expf(d);
        if ((lane & 3) == 0) attBuf[(size_t)ei.x * HEADS + h] = ex;
        norm += ex;
        acc[0] += ex * bf2f(va.x);
        acc[1] += ex * bf2f(va.y);
        acc[2] += ex * bf2f(va.z);
        acc[3] += ex * bf2f(va.w);
        acc[4] += ex * bf2f(vb.x);
        acc[5] += ex * bf2f(vb.y);
        acc[6] += ex * bf2f(vb.z);
        acc[7] += ex * bf2f(vb.w);
    }

    float inv = 1.f / (norm + 1e-8f);
    if ((lane & 3) == 0) invNorm[(size_t)node * HEADS + h] = inv;
    float* op = out + (size_t)node * DIM + lane * 8;
    *(float4*)(op)     = make_float4(acc[0] * inv, acc[1] * inv,
                                     acc[2] * inv, acc[3] * inv);
    *(float4*)(op + 4) = make_float4(acc[4] * inv, acc[5] * inv,
                                     acc[6] * inv, acc[7] * inv);
}

// ---------------------------------------------------------------------------
// att_scale: one thread per EDGE: float4 RMW of attBuf[e][0..3] with one
// float4 gather of invNorm[rows[e]].
// ---------------------------------------------------------------------------
__global__ __launch_bounds__(256)
void att_scale(float* __restrict__ attBuf, const float* __restrict__ invNorm,
               const int* __restrict__ rows, int E)
{
    int e = blockIdx.x * 256 + threadIdx.x;
    if (e >= E) return;
    int r = rows[e];
    float4 inv = *(const float4*)(invNorm + (size_t)r * 4);
    float4 a = *(float4*)(attBuf + (size_t)e * 4);
    a.x *= inv.x; a.y *= inv.y; a.z *= inv.z; a.w *= inv.w;
    *(float4*)(attBuf + (size_t)e * 4) = a;
}

// ---------------------------------------------------------------------------
// kernel_launch
// ws: Qb bf16 [N*128] | KVb bf16 [N*256] | WtHi,WtLo bf16 [3*128*128]*2
//     | invNorm f32 [N*4] | rowPtr[N+1] | blockSums[128] | cursor[N]
//     | edgeInfo int2[E] | degree[N]
// ---------------------------------------------------------------------------
extern "C" void kernel_launch(void* const* d_in, const int* in_sizes, int n_in,
                              void* d_out, int out_size, void* d_ws, size_t ws_size,
                              hipStream_t stream)
{
    const float* emb  = (const float*)d_in[0];
    const float* qW   = (const float*)d_in[1];
    const float* kW   = (const float*)d_in[2];
    const float* vW   = (const float*)d_in[3];
    const int*   rows = (const int*)d_in[4];
    const int*   cols = (const int*)d_in[5];

    const int N = in_sizes[0] / DIM;
    const int E = in_sizes[4];

    float* dout   = (float*)d_out;
    float* outMat = dout;                        // [N,128]
    float* attBuf = dout + (size_t)N * DIM;      // [E,4]

    ushort* Qb   = (ushort*)d_ws;
    ushort* KVb  = Qb + (size_t)N * DIM;
    ushort* WtHi = KVb + (size_t)N * 256;
    ushort* WtLo = WtHi + 3 * DIM * DIM;
    float* invNorm = (float*)(WtLo + 3 * DIM * DIM);
    int* rowPtr    = (int*)(invNorm + (size_t)N * HEADS);
    int* blockSums = rowPtr + (N + 1);
    int* cursor    = blockSums + 128;
    int2* edgeInfo = (int2*)(cursor + N + (((size_t)(cursor + N)) & 4 ? 1 : 0));
    int* degree    = (int*)(edgeInfo + E);

    hipMemsetAsync(degree, 0, (size_t)N * sizeof(int), stream);

    int eblocks = (E + 255) / 256;
    prep<<<192 + eblocks, 256, 0, stream>>>(qW, kW, vW, WtHi, WtLo,
                                            rows, degree, E);

    dim3 ggrid((N + 63) / 64, 2);
    qkv_fused<<<ggrid, 256, 0, stream>>>(emb, WtHi, WtLo, Qb, KVb, N);

    int nb = (N + 1023) / 1024;
    scanA<<<nb, 256, 0, stream>>>(degree, rowPtr, blockSums, N);
    scanC<<<nb, 256, 0, stream>>>(rowPtr, blockSums, cursor, N, E, nb);

    fill_perm<<<eblocks, 256, 0, stream>>>(rows, cols, cursor, edgeInfo, E);

    int gblocks = (N * 16 + 255) / 256;
    csr_fused<<<gblocks, 256, 0, stream>>>(Qb, KVb, rowPtr, edgeInfo,
                                           attBuf, invNorm, outMat, N);

    att_scale<<<eblocks, 256, 0, stream>>>(attBuf, invNorm, rows, E);
}

// Round 16
// 160.595 us; speedup vs baseline: 1.3736x; 1.3736x over previous
//
#include <hip/hip_runtime.h>
#include <cstdint>
#include <cstddef>

#define DIM 128
#define HEADS 4

typedef __attribute__((ext_vector_type(8))) short bf16x8;
typedef __attribute__((ext_vector_type(4))) float f32x4;

__device__ __forceinline__ ushort f2bf(float x) {
    union { float f; uint32_t u; } v; v.f = x;
    uint32_t r = v.u + 0x7FFFu + ((v.u >> 16) & 1u);   // RNE
    return (ushort)(r >> 16);
}
__device__ __forceinline__ float bf2f(ushort h) {
    union { uint32_t u; float f; } v; v.u = ((uint32_t)h) << 16; return v.f;
}

// ---------------------------------------------------------------------------
// prep: fused wtrans (blocks 0..191) + count_degree (blocks 192..)
// wtrans: W[k][col] f32 -> Wt[w][col][k] bf16 hi/lo (transposed for B-frags)
// ---------------------------------------------------------------------------
__global__ __launch_bounds__(256)
void prep(const float* __restrict__ qW, const float* __restrict__ kW,
          const float* __restrict__ vW,
          ushort* __restrict__ WtHi, ushort* __restrict__ WtLo,
          const int* __restrict__ rows, int* __restrict__ degree, int E)
{
    int b = blockIdx.x;
    if (b < 192) {
        int t = b * 256 + threadIdx.x;           // 0..49151
        int w = t >> 14;
        int rem = t & 16383;
        int col = rem >> 7;
        int k = rem & 127;
        const float* W = (w == 0) ? qW : (w == 1) ? kW : vW;
        float x = W[k * DIM + col];
        ushort hi = f2bf(x);
        ushort lo = f2bf(x - bf2f(hi));
        WtHi[t] = hi;                            // [w][col][k]
        WtLo[t] = lo;
    } else {
        int e = (b - 192) * 256 + threadIdx.x;
        if (e < E) atomicAdd(&degree[rows[e]], 1);
    }
}

// ---------------------------------------------------------------------------
// qkv_fused: the R5/R6/R12-measured 57.7us version, verbatim.
// 256 thr = 4 waves (2M x 2N), block = 64 rows x 64 cols (blockIdx.y half).
// K chunked x32: per chunk stage A (f32->hi/lo) + B (all 3 W) in LDS,
// rows padded to APAD=40 ushorts. MFMA per-acc term order: k ascending,
// (hh, lh, hl) per slice -> bit-exact. Epilogue: Q -> Qb[r][128];
// K,V interleaved -> KVb[r][256].
// ---------------------------------------------------------------------------
#define APAD 40   // 32 k + 8 pad (ushorts); row stride 80B

__global__ __launch_bounds__(256)
void qkv_fused(const float* __restrict__ emb,
               const ushort* __restrict__ WtHi, const ushort* __restrict__ WtLo,
               ushort* __restrict__ Qb, ushort* __restrict__ KVb, int N)
{
    __shared__ ushort Ahi[64 * APAD], Alo[64 * APAD];          // 5120B each
    __shared__ ushort Bhi[3 * 64 * APAD], Blo[3 * 64 * APAD];  // 15360B each

    const int tid = threadIdx.x;
    const int wv = tid >> 6;
    const int ln = tid & 63;
    const int l15 = ln & 15;
    const int l4 = ln >> 4;
    const int wm = wv >> 1;             // wave row group (32 rows)
    const int wn = wv & 1;              // wave col group (32 cols)
    const int m0 = blockIdx.x * 64;
    const int c0 = blockIdx.y * 64;     // col half

    f32x4 acc[3][2][2] = {};            // [wsel][fr][n]

    for (int c = 0; c < 4; c++) {       // k chunk: k = c*32 .. +32
        if (c) __syncthreads();
        // ---- stage A chunk: 64 rows x 32 k, f32 -> bf16 hi/lo ----
        {
            int row = tid >> 2;                 // 0..63
            int k8 = (tid & 3) * 8;             // 0,8,16,24
            float4 a0 = make_float4(0.f, 0.f, 0.f, 0.f);
            float4 a1 = a0;
            if (m0 + row < N) {
                const float* src = emb + (size_t)(m0 + row) * DIM + c * 32 + k8;
                a0 = *(const float4*)(src);
                a1 = *(const float4*)(src + 4);
            }
            ushort4 h0, l0, h1, l1;
            h0.x = f2bf(a0.x); l0.x = f2bf(a0.x - bf2f(h0.x));
            h0.y = f2bf(a0.y); l0.y = f2bf(a0.y - bf2f(h0.y));
            h0.z = f2bf(a0.z); l0.z = f2bf(a0.z - bf2f(h0.z));
            h0.w = f2bf(a0.w); l0.w = f2bf(a0.w - bf2f(h0.w));
            h1.x = f2bf(a1.x); l1.x = f2bf(a1.x - bf2f(h1.x));
            h1.y = f2bf(a1.y); l1.y = f2bf(a1.y - bf2f(h1.y));
            h1.z = f2bf(a1.z); l1.z = f2bf(a1.z - bf2f(h1.z));
            h1.w = f2bf(a1.w); l1.w = f2bf(a1.w - bf2f(h1.w));
            int u = row * APAD + k8;
            *(ushort4*)(Ahi + u) = h0; *(ushort4*)(Ahi + u + 4) = h1;
            *(ushort4*)(Alo + u) = l0; *(ushort4*)(Alo + u + 4) = l1;
        }
        // ---- stage B chunk: 3 x 64 cols x 32 k (bf16 pre-split) ----
#pragma unroll
        for (int p = 0; p < 3; p++) {
            int idx = tid + p * 256;            // 0..767, 8 ushorts each
            int flat = idx * 8;                 // 0..6136
            int w = flat >> 11;                 // /2048 (64*32)
            int rem = flat & 2047;
            int col = rem >> 5;
            int kk8 = rem & 31;                 // 0,8,16,24
            size_t goff = (size_t)w * 16384 + (size_t)(c0 + col) * DIM + c * 32 + kk8;
            uint4 hv = *(const uint4*)(WtHi + goff);
            uint4 lv = *(const uint4*)(WtLo + goff);
            int u = (w * 64 + col) * APAD + kk8;
            *(uint4*)(Bhi + u) = hv;
            *(uint4*)(Blo + u) = lv;
        }
        __syncthreads();

        // ---- MFMA: A frag row=wm*32+fr*16+l15, k=l4*8..+8 ----
        bf16x8 ah[2], al[2];
#pragma unroll
        for (int fr = 0; fr < 2; fr++) {
            int u = (wm * 32 + fr * 16 + l15) * APAD + l4 * 8;
            ah[fr] = *(bf16x8*)(Ahi + u);
            al[fr] = *(bf16x8*)(Alo + u);
        }
#pragma unroll
        for (int w = 0; w < 3; w++) {
#pragma unroll
            for (int n = 0; n < 2; n++) {
                int u = (w * 64 + wn * 32 + n * 16 + l15) * APAD + l4 * 8;
                bf16x8 bh = *(bf16x8*)(Bhi + u);
                bf16x8 bl = *(bf16x8*)(Blo + u);
#pragma unroll
                for (int fr = 0; fr < 2; fr++) {
                    acc[w][fr][n] = __builtin_amdgcn_mfma_f32_16x16x32_bf16(ah[fr], bh, acc[w][fr][n], 0, 0, 0);
                    acc[w][fr][n] = __builtin_amdgcn_mfma_f32_16x16x32_bf16(al[fr], bh, acc[w][fr][n], 0, 0, 0);
                    acc[w][fr][n] = __builtin_amdgcn_mfma_f32_16x16x32_bf16(ah[fr], bl, acc[w][fr][n], 0, 0, 0);
                }
            }
        }
    }

    // ---- epilogue: C/D layout col=lane&15, row=(lane>>4)*4+j ----
#pragma unroll
    for (int w = 0; w < 3; w++) {
#pragma unroll
        for (int fr = 0; fr < 2; fr++) {
            int rbase = m0 + wm * 32 + fr * 16 + l4 * 4;
#pragma unroll
            for (int n = 0; n < 2; n++) {
                int col = c0 + wn * 32 + n * 16 + l15;
#pragma unroll
                for (int j = 0; j < 4; j++) {
                    int r = rbase + j;
                    if (r < N) {
                        ushort val = f2bf(acc[w][fr][n][j]);
                        if (w == 0) Qb[(size_t)r * DIM + col] = val;
                        else        KVb[(size_t)r * 256 + (w - 1) * 128 + col] = val;
                    }
                }
            }
        }
    }
}

// ---------------------------------------------------------------------------
// CSR build: scanA (per-1024 exclusive scan + raw segment totals) then
// scanC (merged scanB: each block tree-reduces segSums[0..bid) itself).
// ---------------------------------------------------------------------------
__global__ __launch_bounds__(256)
void scanA(const int* __restrict__ degree, int* __restrict__ rowPtr,
           int* __restrict__ blockSums, int N)
{
    __shared__ int s[256];
    const int tid = threadIdx.x;
    const int base = blockIdx.x * 1024 + tid * 4;
    int d[4];
    int tsum = 0;
#pragma unroll
    for (int i = 0; i < 4; i++) {
        d[i] = (base + i < N) ? degree[base + i] : 0;
        tsum += d[i];
    }
    s[tid] = tsum;
    __syncthreads();
    for (int off = 1; off < 256; off <<= 1) {
        int v = (tid >= off) ? s[tid - off] : 0;
        __syncthreads();
        s[tid] += v;
        __syncthreads();
    }
    if (tid == 255) blockSums[blockIdx.x] = s[255];   // raw block total
    int running = s[tid] - tsum;
#pragma unroll
    for (int i = 0; i < 4; i++) {
        if (base + i < N) rowPtr[base + i] = running;
        running += d[i];
    }
}

__global__ __launch_bounds__(256)
void scanC(int* __restrict__ rowPtr, const int* __restrict__ blockSums,
           int* __restrict__ cursor, int N, int E, int nb)
{
    __shared__ int s[128];
    const int tid = threadIdx.x;
    const int bid = blockIdx.x;
    if (tid < 128) {
        int lim = (bid < nb) ? bid : nb;
        s[tid] = (tid < lim) ? blockSums[tid] : 0;
    }
    __syncthreads();
    for (int off = 64; off > 0; off >>= 1) {
        if (tid < off) s[tid] += s[tid + off];
        __syncthreads();
    }
    const int off = s[0];
    const int base = bid * 1024 + tid * 4;
#pragma unroll
    for (int i = 0; i < 4; i++) {
        int idx = base + i;
        if (idx < N) {
            int v = rowPtr[idx] + off;
            rowPtr[idx] = v;
            cursor[idx] = v;
        }
    }
    if (bid == 0 && tid == 0) rowPtr[N] = E;
}

// fill_perm: pack (edge id, col) into one int2 -> single 8B scattered store.
__global__ __launch_bounds__(256)
void fill_perm(const int* __restrict__ rows, const int* __restrict__ cols,
               int* __restrict__ cursor, int2* __restrict__ edgeInfo, int E)
{
    int e = blockIdx.x * 256 + threadIdx.x;
    if (e >= E) return;
    int pos = atomicAdd(&cursor[rows[e]], 1);
    edgeInfo[pos] = make_int2(e, cols[e]);
}

// ---------------------------------------------------------------------------
// csr_fused: 16 lanes per node (8 dims/lane), 4 nodes per wave. Edge loop
// UNROLL-4 (avg degree = 4): up to 16 independent gathers in flight/node.
// Per-edge accumulation order sequential in p -> bit-exact.
// edgeInfo int2 = (e, col): one 8B broadcast load per edge.
// ---------------------------------------------------------------------------
__global__ __launch_bounds__(256)
void csr_fused(const ushort* __restrict__ Qb, const ushort* __restrict__ KVb,
               const int* __restrict__ rowPtr, const int2* __restrict__ edgeInfo,
               float* __restrict__ attBuf, float* __restrict__ invNorm,
               float* __restrict__ out, int N)
{
    int t = blockIdx.x * 256 + threadIdx.x;
    int node = t >> 4;
    int lane = t & 15;                  // 16 lanes/node
    if (node >= N) return;

    const int start = rowPtr[node];
    const int end   = rowPtr[node + 1];
    const int h = lane >> 2;            // head (4 lanes each)

    const ushort* qp = Qb + (size_t)node * DIM + lane * 8;
    ushort4 qu0 = *(const ushort4*)(qp);
    ushort4 qu1 = *(const ushort4*)(qp + 4);
    float q[8] = {bf2f(qu0.x), bf2f(qu0.y), bf2f(qu0.z), bf2f(qu0.w),
                  bf2f(qu1.x), bf2f(qu1.y), bf2f(qu1.z), bf2f(qu1.w)};

    float norm = 0.f;
    float acc[8] = {0.f, 0.f, 0.f, 0.f, 0.f, 0.f, 0.f, 0.f};

    int p = start;
    for (; p + 4 <= end; p += 4) {
        int2 ei[4];
#pragma unroll
        for (int u = 0; u < 4; u++) ei[u] = edgeInfo[p + u];
        ushort4 ka[4], kb[4], va[4], vb[4];
#pragma unroll
        for (int u = 0; u < 4; u++) {
            const ushort* kv = KVb + (size_t)ei[u].y * 256 + lane * 8;
            ka[u] = *(const ushort4*)(kv);
            kb[u] = *(const ushort4*)(kv + 4);
            va[u] = *(const ushort4*)(kv + 128);
            vb[u] = *(const ushort4*)(kv + 132);
        }
        float d[4];
#pragma unroll
        for (int u = 0; u < 4; u++) {
            d[u] = bf2f(ka[u].x) * q[0] + bf2f(ka[u].y) * q[1]
                 + bf2f(ka[u].z) * q[2] + bf2f(ka[u].w) * q[3]
                 + bf2f(kb[u].x) * q[4] + bf2f(kb[u].y) * q[5]
                 + bf2f(kb[u].z) * q[6] + bf2f(kb[u].w) * q[7];
        }
#pragma unroll
        for (int u = 0; u < 4; u++) d[u] += __shfl_xor(d[u], 1, 64);
#pragma unroll
        for (int u = 0; u < 4; u++) d[u] += __shfl_xor(d[u], 2, 64);
        float ex[4];
#pragma unroll
        for (int u = 0; u < 4; u++) {
            float dd = fminf(fmaxf(d[u], -10.f), 10.f);
            ex[u] = __expf(dd);
        }
        if ((lane & 3) == 0) {
#pragma unroll
            for (int u = 0; u < 4; u++)
                attBuf[(size_t)ei[u].x * HEADS + h] = ex[u];
        }
#pragma unroll
        for (int u = 0; u < 4; u++) {
            norm += ex[u];
            acc[0] += ex[u] * bf2f(va[u].x);
            acc[1] += ex[u] * bf2f(va[u].y);
            acc[2] += ex[u] * bf2f(va[u].z);
            acc[3] += ex[u] * bf2f(va[u].w);
            acc[4] += ex[u] * bf2f(vb[u].x);
            acc[5] += ex[u] * bf2f(vb[u].y);
            acc[6] += ex[u] * bf2f(vb[u].z);
            acc[7] += ex[u] * bf2f(vb[u].w);
        }
    }
    for (; p < end; p++) {
        int2 ei = edgeInfo[p];
        const ushort* kv = KVb + (size_t)ei.y * 256 + lane * 8;
        ushort4 ka = *(const ushort4*)(kv);
        ushort4 kb = *(const ushort4*)(kv + 4);
        ushort4 va = *(const ushort4*)(kv + 128);
        ushort4 vb = *(const ushort4*)(kv + 132);
        float d = bf2f(ka.x) * q[0] + bf2f(ka.y) * q[1]
                + bf2f(ka.z) * q[2] + bf2f(ka.w) * q[3]
                + bf2f(kb.x) * q[4] + bf2f(kb.y) * q[5]
                + bf2f(kb.z) * q[6] + bf2f(kb.w) * q[7];
        d += __shfl_xor(d, 1, 64);
        d += __shfl_xor(d, 2, 64);
        d = fminf(fmaxf(d, -10.f), 10.f);
        float ex = __expf(d);
        if ((lane & 3) == 0) attBuf[(size_t)ei.x * HEADS + h] = ex;
        norm += ex;
        acc[0] += ex * bf2f(va.x);
        acc[1] += ex * bf2f(va.y);
        acc[2] += ex * bf2f(va.z);
        acc[3] += ex * bf2f(va.w);
        acc[4] += ex * bf2f(vb.x);
        acc[5] += ex * bf2f(vb.y);
        acc[6] += ex * bf2f(vb.z);
        acc[7] += ex * bf2f(vb.w);
    }

    float inv = 1.f / (norm + 1e-8f);
    if ((lane & 3) == 0) invNorm[(size_t)node * HEADS + h] = inv;
    float* op = out + (size_t)node * DIM + lane * 8;
    *(float4*)(op)     = make_float4(acc[0] * inv, acc[1] * inv,
                                     acc[2] * inv, acc[3] * inv);
    *(float4*)(op + 4) = make_float4(acc[4] * inv, acc[5] * inv,
                                     acc[6] * inv, acc[7] * inv);
}

// ---------------------------------------------------------------------------
// att_scale: one thread per EDGE: float4 RMW of attBuf[e][0..3] with one
// float4 gather of invNorm[rows[e]].
// ---------------------------------------------------------------------------
__global__ __launch_bounds__(256)
void att_scale(float* __restrict__ attBuf, const float* __restrict__ invNorm,
               const int* __restrict__ rows, int E)
{
    int e = blockIdx.x * 256 + threadIdx.x;
    if (e >= E) return;
    int r = rows[e];
    float4 inv = *(const float4*)(invNorm + (size_t)r * 4);
    float4 a = *(float4*)(attBuf + (size_t)e * 4);
    a.x *= inv.x; a.y *= inv.y; a.z *= inv.z; a.w *= inv.w;
    *(float4*)(attBuf + (size_t)e * 4) = a;
}

// ---------------------------------------------------------------------------
// kernel_launch
// ws: Qb bf16 [N*128] | KVb bf16 [N*256] | WtHi,WtLo bf16 [3*128*128]*2
//     | invNorm f32 [N*4] | rowPtr[N+1] | blockSums[128] | cursor[N]
//     | edgeInfo int2[E] | degree[N]
// ---------------------------------------------------------------------------
extern "C" void kernel_launch(void* const* d_in, const int* in_sizes, int n_in,
                              void* d_out, int out_size, void* d_ws, size_t ws_size,
                              hipStream_t stream)
{
    const float* emb  = (const float*)d_in[0];
    const float* qW   = (const float*)d_in[1];
    const float* kW   = (const float*)d_in[2];
    const float* vW   = (const float*)d_in[3];
    const int*   rows = (const int*)d_in[4];
    const int*   cols = (const int*)d_in[5];

    const int N = in_sizes[0] / DIM;
    const int E = in_sizes[4];

    float* dout   = (float*)d_out;
    float* outMat = dout;                        // [N,128]
    float* attBuf = dout + (size_t)N * DIM;      // [E,4]

    ushort* Qb   = (ushort*)d_ws;
    ushort* KVb  = Qb + (size_t)N * DIM;
    ushort* WtHi = KVb + (size_t)N * 256;
    ushort* WtLo = WtHi + 3 * DIM * DIM;
    float* invNorm = (float*)(WtLo + 3 * DIM * DIM);
    int* rowPtr    = (int*)(invNorm + (size_t)N * HEADS);
    int* blockSums = rowPtr + (N + 1);
    int* cursor    = blockSums + 128;
    int2* edgeInfo = (int2*)(cursor + N + (((size_t)(cursor + N)) & 4 ? 1 : 0));
    int* degree    = (int*)(edgeInfo + E);

    hipMemsetAsync(degree, 0, (size_t)N * sizeof(int), stream);

    int eblocks = (E + 255) / 256;
    prep<<<192 + eblocks, 256, 0, stream>>>(qW, kW, vW, WtHi, WtLo,
                                            rows, degree, E);

    dim3 ggrid((N + 63) / 64, 2);
    qkv_fused<<<ggrid, 256, 0, stream>>>(emb, WtHi, WtLo, Qb, KVb, N);

    int nb = (N + 1023) / 1024;
    scanA<<<nb, 256, 0, stream>>>(degree, rowPtr, blockSums, N);
    scanC<<<nb, 256, 0, stream>>>(rowPtr, blockSums, cursor, N, E, nb);

    fill_perm<<<eblocks, 256, 0, stream>>>(rows, cols, cursor, edgeInfo, E);

    int gblocks = (N * 16 + 255) / 256;
    csr_fused<<<gblocks, 256, 0, stream>>>(Qb, KVb, rowPtr, edgeInfo,
                                           attBuf, invNorm, outMat, N);

    att_scale<<<eblocks, 256, 0, stream>>>(attBuf, invNorm, rows, E);
}